// Round 6
// baseline (6875.631 us; speedup 1.0000x reference)
//
#include <hip/hip_runtime.h>
#include <hip/hip_bf16.h>

#define B_   512
#define L_   64
#define D_   16
#define H_   256
#define V_   512
#define STEPS_ 64
#define DT_  0.984375f
#define LOSC 2048.0f          // lo-term scale 2^11
#define LOSC_INV (1.0f/2048.0f)

typedef _Float16 half_t;
typedef __attribute__((ext_vector_type(8))) _Float16 half8;
typedef __attribute__((ext_vector_type(4))) float f32x4;
typedef unsigned long long u64;

__device__ __forceinline__ void split16(float x, half_t& hi, half_t& lo) {
    half_t h = (half_t)x;
    hi = h;
    lo = (half_t)((x - (float)h) * LOSC);
}

// ---- cache-bypassing (sc0 sc1) accessors: coherent across XCDs with NO fences ----
__device__ __forceinline__ u64 ld_byp_u64(const void* p) {
    return __hip_atomic_load((const u64*)p, __ATOMIC_RELAXED, __HIP_MEMORY_SCOPE_SYSTEM);
}
__device__ __forceinline__ void st_byp_u64(void* p, u64 v) {
    __hip_atomic_store((u64*)p, v, __ATOMIC_RELAXED, __HIP_MEMORY_SCOPE_SYSTEM);
}
__device__ __forceinline__ half8 ld_frag_byp(const half_t* p) {
    u64 t[2];
    t[0] = ld_byp_u64(p);
    t[1] = ld_byp_u64((const char*)p + 8);
    return *(half8*)t;
}
__device__ __forceinline__ void st_frag_byp(half_t* p, half8 v) {
    u64 t[2];
    *(half8*)t = v;
    st_byp_u64(p, t[0]);
    st_byp_u64((char*)p + 8, t[1]);
}
__device__ __forceinline__ float ld_byp_f32(const float* p) {
    return __hip_atomic_load(p, __ATOMIC_RELAXED, __HIP_MEMORY_SCOPE_SYSTEM);
}
__device__ __forceinline__ void st_byp_f32(float* p, float v) {
    __hip_atomic_store(p, v, __ATOMIC_RELAXED, __HIP_MEMORY_SCOPE_SYSTEM);
}

// ---------------- prep kernels ----------------

// Pack W [N][K] fp32 into MFMA B-fragment order, f16 hi + scaled-lo:
// slot idx = ((g*Kc + c)*64 + l)*8 + j  <-  W[g*16 + (l&15)][c*32 + (l>>4)*8 + j]
__global__ void pack_frag_kernel(const float* __restrict__ src, half_t* __restrict__ hi,
                                 half_t* __restrict__ lo, int Kc, int K, int total) {
    int idx = blockIdx.x * 256 + threadIdx.x;
    if (idx >= total) return;
    int j = idx & 7;
    int l = (idx >> 3) & 63;
    int gc = idx >> 9;
    int c = gc % Kc, g = gc / Kc;
    int n = (g << 4) + (l & 15);
    int k = (c << 5) + ((l >> 4) << 3) + j;
    float w = src[n * K + k];
    half_t h, lw;
    split16(w, h, lw);
    hi[idx] = h;
    lo[idx] = lw;
}

// h0 = tanh(X0 @ W0^T + b0)  (bypass store so the persistent kernel sees it)
__global__ void h0_kernel(const float* __restrict__ coeffs, const float* __restrict__ W0,
                          const float* __restrict__ b0, float* __restrict__ hout) {
    int b = blockIdx.x;
    int hh = threadIdx.x;
    float acc = b0[hh];
    #pragma unroll
    for (int d = 0; d < 16; d++)
        acc += coeffs[b * ((L_ - 1) * 4 * D_) + d] * W0[hh * 16 + d];
    st_byp_f32(&hout[b * H_ + hh], tanhf(acc));
}

// ---------------- persistent kernel ----------------

struct NcdeParams {
    const float* coeffs;
    const half_t* W1h; const half_t* W1l; const float* b1; const float* g1; const float* be1;
    const half_t* W2h; const half_t* W2l; const float* b2; const float* g2; const float* be2;
    const half_t* W3h; const float* b3;
    float* hbuf;
    half_t* t2;          // single-f16 post-LN2 A-fragments [gm 32][c 16][l 64][8]
    unsigned* bar;
};

// smem layout (bytes), phase A view:
//   A1h @ 0      (8 KB)   A1l @ 8192 (8 KB)
//   zs  @ 16384  (16x517 fp32 = 33088)
//   A2h @ 49664  (16 KB)  A2l @ 66048 (16 KB)
//   part@ 82432  (4 KB)   mr @ 86528  rrs @ 86656
// phase B view: Ah @ 0 (16 KB), dxs @ 16384 (16x17 f32)
#define SMEM_BYTES 86784

__device__ __forceinline__ void grid_barrier(unsigned* bar, unsigned target) {
    __syncthreads();   // drains vmcnt -> all byp stores at coherence point
    if (threadIdx.x == 0) {
        __hip_atomic_fetch_add(bar, 1u, __ATOMIC_RELAXED, __HIP_MEMORY_SCOPE_SYSTEM);
        while (__hip_atomic_load(bar, __ATOMIC_RELAXED, __HIP_MEMORY_SCOPE_SYSTEM) < target)
            __builtin_amdgcn_s_sleep(8);
    }
    __syncthreads();
}

// Phase A: full fused MLP12 for 16 rows. 32 blocks (bid<32), 512 threads.
// t2 = LN2(tanh(LN1(tanh(h@W1^T+b1))@W2^T+b2)) -> single-f16 fragments (bypass).
__device__ __forceinline__ void phaseA(int bid, char* smem, const NcdeParams& P) {
    half_t* A1h = (half_t*)smem;
    half_t* A1l = (half_t*)(smem + 8192);
    float (*zs)[517] = (float(*)[517])(smem + 16384);
    half_t* A2h = (half_t*)(smem + 49664);
    half_t* A2l = (half_t*)(smem + 66048);
    float* part = (float*)(smem + 82432);
    float* mr   = (float*)(smem + 86528);
    float* rrs  = (float*)(smem + 86656);
    const int tid = threadIdx.x, wv = tid >> 6, l = tid & 63;
    const int row0 = bid << 4;

    // 1. load h (bypass) -> A1 hi/lo fragments (K=256: 8 chunks)
    {
        int c = tid >> 6;
        const float* src = P.hbuf + (row0 + (l & 15)) * H_ + (c << 5) + ((l >> 4) << 3);
        u64 q[4];
        q[0] = ld_byp_u64(src);
        q[1] = ld_byp_u64(src + 2);
        q[2] = ld_byp_u64(src + 4);
        q[3] = ld_byp_u64(src + 6);
        const float* xx = (const float*)q;
        half8 hv, lv;
        #pragma unroll
        for (int j = 0; j < 8; j++) { half_t a, b; split16(xx[j], a, b); hv[j] = a; lv[j] = b; }
        int base = ((c << 6) + l) << 3;
        *(half8*)&A1h[base] = hv;
        *(half8*)&A1l[base] = lv;
    }
    __syncthreads();

    // 2. GEMM1 (hi/lo x hi/lo, 3 MFMA): wave owns n-groups 4wv..4wv+3
    f32x4 acc[4], accl[4];
    #pragma unroll
    for (int i = 0; i < 4; i++) { acc[i] = (f32x4){0,0,0,0}; accl[i] = (f32x4){0,0,0,0}; }
    for (int c = 0; c < 8; c++) {
        half8 ah = *(const half8*)&A1h[((c << 6) + l) << 3];
        half8 al = *(const half8*)&A1l[((c << 6) + l) << 3];
        #pragma unroll
        for (int i = 0; i < 4; i++) {
            int gn = (wv << 2) + i;
            half8 bh = *(const half8*)&P.W1h[(((gn << 3) + c) * 64 + l) * 8];
            half8 bl = *(const half8*)&P.W1l[(((gn << 3) + c) * 64 + l) * 8];
            acc[i]  = __builtin_amdgcn_mfma_f32_16x16x32_f16(ah, bh, acc[i],  0, 0, 0);
            accl[i] = __builtin_amdgcn_mfma_f32_16x16x32_f16(ah, bl, accl[i], 0, 0, 0);
            accl[i] = __builtin_amdgcn_mfma_f32_16x16x32_f16(al, bh, accl[i], 0, 0, 0);
        }
    }
    // 3. + b1, tanh -> zs
    #pragma unroll
    for (int i = 0; i < 4; i++) {
        int col = (((wv << 2) + i) << 4) + (l & 15);
        float bb = P.b1[col];
        #pragma unroll
        for (int j = 0; j < 4; j++)
            zs[((l >> 4) << 2) + j][col] = tanhf(acc[i][j] + accl[i][j] * LOSC_INV + bb);
    }
    __syncthreads();

    // 4. LN1: wave wv handles rows 2wv, 2wv+1
    #pragma unroll
    for (int rr = 0; rr < 2; rr++) {
        int r = (wv << 1) + rr;
        float v[8], s = 0.f, ss = 0.f;
        #pragma unroll
        for (int j = 0; j < 8; j++) { v[j] = zs[r][l + (j << 6)]; s += v[j]; ss += v[j] * v[j]; }
        #pragma unroll
        for (int o = 32; o; o >>= 1) { s += __shfl_xor(s, o); ss += __shfl_xor(ss, o); }
        float mn = s * (1.f / 512.f);
        float rstd = rsqrtf(ss * (1.f / 512.f) - mn * mn + 1e-5f);
        #pragma unroll
        for (int j = 0; j < 8; j++) {
            int cc = l + (j << 6);
            zs[r][cc] = (v[j] - mn) * rstd * P.g1[cc] + P.be1[cc];
        }
    }
    __syncthreads();

    // 5. pack z1 -> A2 hi/lo fragments (K=512: 16 chunks)
    #pragma unroll
    for (int cc = 0; cc < 2; cc++) {
        int c = ((tid >> 6) << 1) + cc;
        half8 hv, lv;
        #pragma unroll
        for (int j = 0; j < 8; j++) {
            float v = zs[l & 15][(c << 5) + ((l >> 4) << 3) + j];
            half_t a, b; split16(v, a, b); hv[j] = a; lv[j] = b;
        }
        int base = ((c << 6) + l) << 3;
        *(half8*)&A2h[base] = hv;
        *(half8*)&A2l[base] = lv;
    }
    __syncthreads();

    // 6. GEMM2
    #pragma unroll
    for (int i = 0; i < 4; i++) { acc[i] = (f32x4){0,0,0,0}; accl[i] = (f32x4){0,0,0,0}; }
    for (int c = 0; c < 16; c++) {
        half8 ah = *(const half8*)&A2h[((c << 6) + l) << 3];
        half8 al = *(const half8*)&A2l[((c << 6) + l) << 3];
        #pragma unroll
        for (int i = 0; i < 4; i++) {
            int gn = (wv << 2) + i;
            half8 bh = *(const half8*)&P.W2h[(((gn << 4) + c) * 64 + l) * 8];
            half8 bl = *(const half8*)&P.W2l[(((gn << 4) + c) * 64 + l) * 8];
            acc[i]  = __builtin_amdgcn_mfma_f32_16x16x32_f16(ah, bh, acc[i],  0, 0, 0);
            accl[i] = __builtin_amdgcn_mfma_f32_16x16x32_f16(ah, bl, accl[i], 0, 0, 0);
            accl[i] = __builtin_amdgcn_mfma_f32_16x16x32_f16(al, bh, accl[i], 0, 0, 0);
        }
    }
    // 7. + b2, tanh -> zs
    #pragma unroll
    for (int i = 0; i < 4; i++) {
        int col = (((wv << 2) + i) << 4) + (l & 15);
        float bb = P.b2[col];
        #pragma unroll
        for (int j = 0; j < 4; j++)
            zs[((l >> 4) << 2) + j][col] = tanhf(acc[i][j] + accl[i][j] * LOSC_INV + bb);
    }
    __syncthreads();

    // 8. LN2
    #pragma unroll
    for (int rr = 0; rr < 2; rr++) {
        int r = (wv << 1) + rr;
        float v[8], s = 0.f, ss = 0.f;
        #pragma unroll
        for (int j = 0; j < 8; j++) { v[j] = zs[r][l + (j << 6)]; s += v[j]; ss += v[j] * v[j]; }
        #pragma unroll
        for (int o = 32; o; o >>= 1) { s += __shfl_xor(s, o); ss += __shfl_xor(ss, o); }
        float mn = s * (1.f / 512.f);
        float rstd = rsqrtf(ss * (1.f / 512.f) - mn * mn + 1e-5f);
        #pragma unroll
        for (int j = 0; j < 8; j++) {
            int cc = l + (j << 6);
            zs[r][cc] = (v[j] - mn) * rstd * P.g2[cc] + P.be2[cc];
        }
    }
    __syncthreads();

    // 9. pack t2 (single f16) -> bypass store
    #pragma unroll
    for (int cc = 0; cc < 2; cc++) {
        int c = ((tid >> 6) << 1) + cc;
        half8 hv;
        #pragma unroll
        for (int j = 0; j < 8; j++)
            hv[j] = (half_t)zs[l & 15][(c << 5) + ((l >> 4) << 3) + j];
        st_frag_byp(&P.t2[(((bid << 4) + c) * 64 + l) * 8], hv);
    }
}

// Phase B: vf = t2 @ W3^T + b3 (single f16 x single f16); h += dt*(vf . dX).
// 256 blocks: rg = bid>>3 (16 rows), cg = bid&7 (512 cols; same-cg blocks share one XCD).
__device__ __forceinline__ void phaseB(int bid, char* smem, const NcdeParams& P,
                                       int ii, float frac) {
    half_t* Ah = (half_t*)smem;
    float (*dxs)[17] = (float(*)[17])(smem + 16384);
    const int tid = threadIdx.x, w = tid >> 6, l = tid & 63;
    const int rg = bid >> 3, cg = bid & 7;
    const int row0 = rg << 4;

    if (tid < 256) {
        int r = tid >> 4, d = tid & 15;
        int base = ((row0 + r) * (L_ - 1) + ii) * 64 + d;
        float c1 = P.coeffs[base + 16], c2 = P.coeffs[base + 32], c3 = P.coeffs[base + 48];
        dxs[r][d] = c1 + 2.0f * frac * c2 + 3.0f * (frac * frac) * c3;
    }
    // load t2 fragments (bypass) -> LDS
    #pragma unroll
    for (int cc = 0; cc < 2; cc++) {
        int c = ((tid >> 6) << 1) + cc;
        half8 v = ld_frag_byp(&P.t2[(((rg << 4) + c) * 64 + l) * 8]);
        *(half8*)&Ah[((c << 6) + l) << 3] = v;
    }
    __syncthreads();

    f32x4 acc[4];
    #pragma unroll
    for (int i = 0; i < 4; i++) acc[i] = (f32x4){0, 0, 0, 0};
    for (int c = 0; c < 16; c++) {
        half8 ah = *(const half8*)&Ah[((c << 6) + l) << 3];
        #pragma unroll
        for (int i = 0; i < 4; i++) {
            int gn = (cg << 5) + (w << 2) + i;
            half8 bh = *(const half8*)&P.W3h[(((gn << 4) + c) * 64 + l) * 8];
            acc[i] = __builtin_amdgcn_mfma_f32_16x16x32_f16(ah, bh, acc[i], 0, 0, 0);
        }
    }

    // epilogue: + b3, contract with dX over d=l&15, reduce 16 lanes, unique-writer h RMW
    const int d = l & 15;
    #pragma unroll
    for (int i = 0; i < 4; i++) {
        int hh = (cg << 5) + (w << 2) + i;
        float b3v = P.b3[(hh << 4) + d];
        #pragma unroll
        for (int j = 0; j < 4; j++) {
            int rl = ((l >> 4) << 2) + j;
            float s = (acc[i][j] + b3v) * dxs[rl][d];
            s += __shfl_xor(s, 1);
            s += __shfl_xor(s, 2);
            s += __shfl_xor(s, 4);
            s += __shfl_xor(s, 8);
            if (d == 0) {
                float* hp = &P.hbuf[(row0 + rl) * H_ + hh];
                st_byp_f32(hp, ld_byp_f32(hp) + s * DT_);
            }
        }
    }
}

__global__ __launch_bounds__(512) void ncde_persistent(NcdeParams P) {
    __shared__ __align__(16) char smem[SMEM_BYTES];
    const int bid = blockIdx.x;
    unsigned epoch = 0;
    for (int s = 0; s < STEPS_; s++) {
        float t = (float)s * 0.984375f;      // exact in fp32
        int ii = (int)t;
        if (ii > L_ - 2) ii = L_ - 2;
        float frac = t - (float)ii;

        if (bid < 32) phaseA(bid, smem, P);
        grid_barrier(P.bar, ++epoch * 256u);

        phaseB(bid, smem, P, ii, frac);
        grid_barrier(P.bar, ++epoch * 256u);
    }
}

// ---------------- launch ----------------

extern "C" void kernel_launch(void* const* d_in, const int* in_sizes, int n_in,
                              void* d_out, int out_size, void* d_ws, size_t ws_size,
                              hipStream_t stream) {
    const float* coeffs = (const float*)d_in[0];
    const float* W0  = (const float*)d_in[1];
    const float* b0  = (const float*)d_in[2];
    const float* W1  = (const float*)d_in[3];
    const float* b1  = (const float*)d_in[4];
    const float* g1  = (const float*)d_in[5];
    const float* be1 = (const float*)d_in[6];
    const float* W2  = (const float*)d_in[7];
    const float* b2  = (const float*)d_in[8];
    const float* g2  = (const float*)d_in[9];
    const float* be2 = (const float*)d_in[10];
    const float* W3  = (const float*)d_in[11];
    const float* b3  = (const float*)d_in[12];

    char* w = (char*)d_ws;
    float*  hbuf = (float*)(w);                        // 512 KB
    half_t* t2   = (half_t*)(w + 524288);              // 512 KB
    half_t* W1h  = (half_t*)(w + 1048576);             // 256 KB
    half_t* W1l  = (half_t*)(w + 1310720);             // 256 KB
    half_t* W2h  = (half_t*)(w + 1572864);             // 512 KB
    half_t* W2l  = (half_t*)(w + 2097152);             // 512 KB
    half_t* W3h  = (half_t*)(w + 2621440);             // 4 MB
    half_t* W3l  = (half_t*)(w + 6815744);             // 4 MB (packed, unused)
    unsigned* bar = (unsigned*)(w + 11010048);         // 64 B

    hipMemsetAsync(bar, 0, 64, stream);
    pack_frag_kernel<<<512, 256, 0, stream>>>(W1, W1h, W1l, 8, H_, V_ * H_);
    pack_frag_kernel<<<1024, 256, 0, stream>>>(W2, W2h, W2l, 16, V_, V_ * V_);
    pack_frag_kernel<<<8192, 256, 0, stream>>>(W3, W3h, W3l, 16, V_, (H_ * D_) * V_);
    h0_kernel<<<B_, H_, 0, stream>>>(coeffs, W0, b0, hbuf);

    NcdeParams prm;
    prm.coeffs = coeffs;
    prm.W1h = W1h; prm.W1l = W1l; prm.b1 = b1; prm.g1 = g1; prm.be1 = be1;
    prm.W2h = W2h; prm.W2l = W2l; prm.b2 = b2; prm.g2 = g2; prm.be2 = be2;
    prm.W3h = W3h; prm.b3 = b3;
    prm.hbuf = hbuf;
    prm.t2 = t2;
    prm.bar = bar;

    ncde_persistent<<<256, 512, 0, stream>>>(prm);

    hipMemcpyAsync(d_out, hbuf, (size_t)B_ * H_ * sizeof(float),
                   hipMemcpyDeviceToDevice, stream);
}

// Round 7
// 2180.568 us; speedup vs baseline: 3.1531x; 3.1531x over previous
//
#include <hip/hip_runtime.h>
#include <hip/hip_bf16.h>

#define B_   512
#define L_   64
#define D_   16
#define H_   256
#define V_   512
#define STEPS_ 64
#define DT_  0.984375f
#define LOSC 2048.0f          // lo-term scale 2^11
#define LOSC_INV (1.0f/2048.0f)

typedef _Float16 half_t;
typedef __attribute__((ext_vector_type(8))) _Float16 half8;
typedef __attribute__((ext_vector_type(4))) float f32x4;

__device__ __forceinline__ void split16(float x, half_t& hi, half_t& lo) {
    half_t h = (half_t)x;
    hi = h;
    lo = (half_t)((x - (float)h) * LOSC);
}

// ---------------- prep kernels ----------------

// Pack W [N][K] fp32 into MFMA B-fragment order, f16 hi + scaled-lo:
// slot idx = ((g*Kc + c)*64 + l)*8 + j  <-  W[g*16 + (l&15)][c*32 + (l>>4)*8 + j]
__global__ void pack_frag_kernel(const float* __restrict__ src, half_t* __restrict__ hi,
                                 half_t* __restrict__ lo, int Kc, int K, int total) {
    int idx = blockIdx.x * 256 + threadIdx.x;
    if (idx >= total) return;
    int j = idx & 7;
    int l = (idx >> 3) & 63;
    int gc = idx >> 9;
    int c = gc % Kc, g = gc / Kc;
    int n = (g << 4) + (l & 15);
    int k = (c << 5) + ((l >> 4) << 3) + j;
    float w = src[n * K + k];
    half_t h, lw;
    split16(w, h, lw);
    hi[idx] = h;
    lo[idx] = lw;
}

// h0 = tanh(X0 @ W0^T + b0)
__global__ void h0_kernel(const float* __restrict__ coeffs, const float* __restrict__ W0,
                          const float* __restrict__ b0, float* __restrict__ hout) {
    int b = blockIdx.x;
    int hh = threadIdx.x;
    float acc = b0[hh];
    #pragma unroll
    for (int d = 0; d < 16; d++)
        acc += coeffs[b * ((L_ - 1) * 4 * D_) + d] * W0[hh * 16 + d];
    hout[b * H_ + hh] = tanhf(acc);
}

// ---------------- per-step kernel A: fused MLP12 ----------------
// 32 blocks x 512 threads; block = 16 batch rows x full V=512.
// t2 = LN2(tanh(LN1(tanh(h@W1^T+b1))@W2^T+b2)) -> single-f16 A-fragments.
__global__ __launch_bounds__(512) void mlp12_kernel(
    const float* __restrict__ hbuf,
    const half_t* __restrict__ W1h, const half_t* __restrict__ W1l,
    const float* __restrict__ b1, const float* __restrict__ g1, const float* __restrict__ be1,
    const half_t* __restrict__ W2h, const half_t* __restrict__ W2l,
    const float* __restrict__ b2, const float* __restrict__ g2, const float* __restrict__ be2,
    half_t* __restrict__ t2)
{
    __shared__ __align__(16) half_t A1h[8 * 64 * 8];     // 8 KB
    __shared__ __align__(16) half_t A1l[8 * 64 * 8];     // 8 KB
    __shared__ float zs[16][517];                        // ~33 KB
    __shared__ __align__(16) half_t A2h[16 * 64 * 8];    // 16 KB
    __shared__ __align__(16) half_t A2l[16 * 64 * 8];    // 16 KB
    const int tid = threadIdx.x, wv = tid >> 6, l = tid & 63;
    const int row0 = blockIdx.x << 4;

    // 1. load h -> A1 hi/lo fragments (K=256: 8 chunks)
    {
        int c = tid >> 6;
        const float* src = hbuf + (row0 + (l & 15)) * H_ + (c << 5) + ((l >> 4) << 3);
        float4 x = *(const float4*)src;
        float4 y = *(const float4*)(src + 4);
        float xx[8] = {x.x, x.y, x.z, x.w, y.x, y.y, y.z, y.w};
        half8 hv, lv;
        #pragma unroll
        for (int j = 0; j < 8; j++) { half_t a, b; split16(xx[j], a, b); hv[j] = a; lv[j] = b; }
        int base = ((c << 6) + l) << 3;
        *(half8*)&A1h[base] = hv;
        *(half8*)&A1l[base] = lv;
    }
    __syncthreads();

    // 2. GEMM1 (hi/lo x hi/lo, 3 MFMA): wave owns n-groups 4wv..4wv+3
    f32x4 acc[4], accl[4];
    #pragma unroll
    for (int i = 0; i < 4; i++) { acc[i] = (f32x4){0,0,0,0}; accl[i] = (f32x4){0,0,0,0}; }
    for (int c = 0; c < 8; c++) {
        half8 ah = *(const half8*)&A1h[((c << 6) + l) << 3];
        half8 al = *(const half8*)&A1l[((c << 6) + l) << 3];
        #pragma unroll
        for (int i = 0; i < 4; i++) {
            int gn = (wv << 2) + i;
            half8 bh = *(const half8*)&W1h[(((gn << 3) + c) * 64 + l) * 8];
            half8 bl = *(const half8*)&W1l[(((gn << 3) + c) * 64 + l) * 8];
            acc[i]  = __builtin_amdgcn_mfma_f32_16x16x32_f16(ah, bh, acc[i],  0, 0, 0);
            accl[i] = __builtin_amdgcn_mfma_f32_16x16x32_f16(ah, bl, accl[i], 0, 0, 0);
            accl[i] = __builtin_amdgcn_mfma_f32_16x16x32_f16(al, bh, accl[i], 0, 0, 0);
        }
    }
    // 3. + b1, tanh -> zs
    #pragma unroll
    for (int i = 0; i < 4; i++) {
        int col = (((wv << 2) + i) << 4) + (l & 15);
        float bb = b1[col];
        #pragma unroll
        for (int j = 0; j < 4; j++)
            zs[((l >> 4) << 2) + j][col] = tanhf(acc[i][j] + accl[i][j] * LOSC_INV + bb);
    }
    __syncthreads();

    // 4. LN1: wave wv handles rows 2wv, 2wv+1
    #pragma unroll
    for (int rr = 0; rr < 2; rr++) {
        int r = (wv << 1) + rr;
        float v[8], s = 0.f, ss = 0.f;
        #pragma unroll
        for (int j = 0; j < 8; j++) { v[j] = zs[r][l + (j << 6)]; s += v[j]; ss += v[j] * v[j]; }
        #pragma unroll
        for (int o = 32; o; o >>= 1) { s += __shfl_xor(s, o); ss += __shfl_xor(ss, o); }
        float mn = s * (1.f / 512.f);
        float rstd = rsqrtf(ss * (1.f / 512.f) - mn * mn + 1e-5f);
        #pragma unroll
        for (int j = 0; j < 8; j++) {
            int cc = l + (j << 6);
            zs[r][cc] = (v[j] - mn) * rstd * g1[cc] + be1[cc];
        }
    }
    __syncthreads();

    // 5. pack z1 -> A2 hi/lo fragments (K=512: 16 chunks)
    #pragma unroll
    for (int cc = 0; cc < 2; cc++) {
        int c = ((tid >> 6) << 1) + cc;
        half8 hv, lv;
        #pragma unroll
        for (int j = 0; j < 8; j++) {
            float v = zs[l & 15][(c << 5) + ((l >> 4) << 3) + j];
            half_t a, b; split16(v, a, b); hv[j] = a; lv[j] = b;
        }
        int base = ((c << 6) + l) << 3;
        *(half8*)&A2h[base] = hv;
        *(half8*)&A2l[base] = lv;
    }
    __syncthreads();

    // 6. GEMM2
    #pragma unroll
    for (int i = 0; i < 4; i++) { acc[i] = (f32x4){0,0,0,0}; accl[i] = (f32x4){0,0,0,0}; }
    for (int c = 0; c < 16; c++) {
        half8 ah = *(const half8*)&A2h[((c << 6) + l) << 3];
        half8 al = *(const half8*)&A2l[((c << 6) + l) << 3];
        #pragma unroll
        for (int i = 0; i < 4; i++) {
            int gn = (wv << 2) + i;
            half8 bh = *(const half8*)&W2h[(((gn << 4) + c) * 64 + l) * 8];
            half8 bl = *(const half8*)&W2l[(((gn << 4) + c) * 64 + l) * 8];
            acc[i]  = __builtin_amdgcn_mfma_f32_16x16x32_f16(ah, bh, acc[i],  0, 0, 0);
            accl[i] = __builtin_amdgcn_mfma_f32_16x16x32_f16(ah, bl, accl[i], 0, 0, 0);
            accl[i] = __builtin_amdgcn_mfma_f32_16x16x32_f16(al, bh, accl[i], 0, 0, 0);
        }
    }
    // 7. + b2, tanh -> zs
    #pragma unroll
    for (int i = 0; i < 4; i++) {
        int col = (((wv << 2) + i) << 4) + (l & 15);
        float bb = b2[col];
        #pragma unroll
        for (int j = 0; j < 4; j++)
            zs[((l >> 4) << 2) + j][col] = tanhf(acc[i][j] + accl[i][j] * LOSC_INV + bb);
    }
    __syncthreads();

    // 8. LN2
    #pragma unroll
    for (int rr = 0; rr < 2; rr++) {
        int r = (wv << 1) + rr;
        float v[8], s = 0.f, ss = 0.f;
        #pragma unroll
        for (int j = 0; j < 8; j++) { v[j] = zs[r][l + (j << 6)]; s += v[j]; ss += v[j] * v[j]; }
        #pragma unroll
        for (int o = 32; o; o >>= 1) { s += __shfl_xor(s, o); ss += __shfl_xor(ss, o); }
        float mn = s * (1.f / 512.f);
        float rstd = rsqrtf(ss * (1.f / 512.f) - mn * mn + 1e-5f);
        #pragma unroll
        for (int j = 0; j < 8; j++) {
            int cc = l + (j << 6);
            zs[r][cc] = (v[j] - mn) * rstd * g2[cc] + be2[cc];
        }
    }
    __syncthreads();

    // 9. pack t2 (single f16) -> global, fragment order [gm 32][c 16][l 64][8]
    #pragma unroll
    for (int cc = 0; cc < 2; cc++) {
        int c = ((tid >> 6) << 1) + cc;
        half8 hv;
        #pragma unroll
        for (int j = 0; j < 8; j++)
            hv[j] = (half_t)zs[l & 15][(c << 5) + ((l >> 4) << 3) + j];
        *(half8*)&t2[(((blockIdx.x << 4) + c) * 64 + l) * 8] = hv;
    }
}

// ---------------- per-step kernel B: stage 3 ----------------
// vf = t2 @ W3^T + b3; h[b,hh] += dt * sum_d vf[b,hh*16+d]*dX[b,d].
// 256 blocks = 8 row-groups (64 rows) x 32 col-groups (128 cols = 8 n-groups).
// Wave w owns n-group gn = cg*8 + w (i.e. one hh); 4 m-frags.
__global__ __launch_bounds__(512) void stage3_kernel(
    const half_t* __restrict__ t2, const half_t* __restrict__ W3h,
    const float* __restrict__ b3, const float* __restrict__ coeffs,
    float* __restrict__ hbuf, int ii, float frac)
{
    __shared__ __align__(16) half_t Ah[4 * 16 * 64 * 8];  // 64 KB: 4 m-frag groups x 16 k-chunks
    __shared__ float dxs[64][17];                          // 4.25 KB
    const int tid = threadIdx.x, w = tid >> 6, l = tid & 63;
    const int rg = blockIdx.x >> 5;      // 0..7  (64 rows)
    const int cg = blockIdx.x & 31;      // 0..31 (128 cols)
    const int row0 = rg << 6;
    const int gn = (cg << 3) + w;        // wave's n-group == hh

    // spline derivative for this block's 64 rows
    for (int idx = tid; idx < 64 * 16; idx += 512) {
        int r = idx >> 4, d = idx & 15;
        int base = ((row0 + r) * (L_ - 1) + ii) * 64 + d;
        float c1 = coeffs[base + 16], c2 = coeffs[base + 32], c3 = coeffs[base + 48];
        dxs[r][d] = c1 + 2.0f * frac * c2 + 3.0f * (frac * frac) * c3;
    }
    // stage t2 tile: gm groups rg*4..rg*4+3 -> 64 KB contiguous copy
    {
        const half_t* src = t2 + ((rg << 2) * 16) * 64 * 8;
        #pragma unroll
        for (int u = 0; u < 8; u++) {
            int off = ((u << 9) + tid) << 3;
            *(half8*)&Ah[off] = *(const half8*)&src[off];
        }
    }
    __syncthreads();

    f32x4 acc[4];
    #pragma unroll
    for (int i = 0; i < 4; i++) acc[i] = (f32x4){0, 0, 0, 0};
    for (int c = 0; c < 16; c++) {
        half8 bh = *(const half8*)&W3h[(((gn << 4) + c) * 64 + l) * 8];
        #pragma unroll
        for (int mf = 0; mf < 4; mf++) {
            half8 ah = *(const half8*)&Ah[(((mf << 4) + c) * 64 + l) * 8];
            acc[mf] = __builtin_amdgcn_mfma_f32_16x16x32_f16(ah, bh, acc[mf], 0, 0, 0);
        }
    }

    // epilogue: + b3, contract with dX over d = l&15, 16-lane reduce, unique-writer h RMW
    const int d = l & 15;
    const float b3v = b3[(gn << 4) + d];
    #pragma unroll
    for (int mf = 0; mf < 4; mf++) {
        #pragma unroll
        for (int j = 0; j < 4; j++) {
            int rl = (mf << 4) + ((l >> 4) << 2) + j;
            float s = (acc[mf][j] + b3v) * dxs[rl][d];
            s += __shfl_xor(s, 1);
            s += __shfl_xor(s, 2);
            s += __shfl_xor(s, 4);
            s += __shfl_xor(s, 8);
            if (d == 0) hbuf[(row0 + rl) * H_ + gn] += s * DT_;
        }
    }
}

// ---------------- launch ----------------

extern "C" void kernel_launch(void* const* d_in, const int* in_sizes, int n_in,
                              void* d_out, int out_size, void* d_ws, size_t ws_size,
                              hipStream_t stream) {
    const float* coeffs = (const float*)d_in[0];
    const float* W0  = (const float*)d_in[1];
    const float* b0  = (const float*)d_in[2];
    const float* W1  = (const float*)d_in[3];
    const float* b1  = (const float*)d_in[4];
    const float* g1  = (const float*)d_in[5];
    const float* be1 = (const float*)d_in[6];
    const float* W2  = (const float*)d_in[7];
    const float* b2  = (const float*)d_in[8];
    const float* g2  = (const float*)d_in[9];
    const float* be2 = (const float*)d_in[10];
    const float* W3  = (const float*)d_in[11];
    const float* b3  = (const float*)d_in[12];

    char* w = (char*)d_ws;
    float*  hbuf = (float*)(w);                        // 512 KB
    half_t* t2   = (half_t*)(w + 524288);              // 512 KB
    half_t* W1h  = (half_t*)(w + 1048576);             // 256 KB
    half_t* W1l  = (half_t*)(w + 1310720);             // 256 KB
    half_t* W2h  = (half_t*)(w + 1572864);             // 512 KB
    half_t* W2l  = (half_t*)(w + 2097152);             // 512 KB
    half_t* W3h  = (half_t*)(w + 2621440);             // 4 MB
    half_t* W3l  = (half_t*)(w + 6815744);             // 4 MB (lo packed, unused by stage3)

    pack_frag_kernel<<<512, 256, 0, stream>>>(W1, W1h, W1l, 8, H_, V_ * H_);
    pack_frag_kernel<<<1024, 256, 0, stream>>>(W2, W2h, W2l, 16, V_, V_ * V_);
    pack_frag_kernel<<<8192, 256, 0, stream>>>(W3, W3h, W3l, 16, V_, (H_ * D_) * V_);
    h0_kernel<<<B_, H_, 0, stream>>>(coeffs, W0, b0, hbuf);

    for (int s = 0; s < STEPS_; s++) {
        float t = (float)s * 0.984375f;      // exact in fp32
        int ii = (int)t;
        if (ii > L_ - 2) ii = L_ - 2;
        float frac = t - (float)ii;
        mlp12_kernel<<<32, 512, 0, stream>>>(hbuf, W1h, W1l, b1, g1, be1,
                                             W2h, W2l, b2, g2, be2, t2);
        stage3_kernel<<<256, 512, 0, stream>>>(t2, W3h, b3, coeffs, hbuf, ii, frac);
    }

    hipMemcpyAsync(d_out, hbuf, (size_t)B_ * H_ * sizeof(float),
                   hipMemcpyDeviceToDevice, stream);
}

// Round 8
// 1698.185 us; speedup vs baseline: 4.0488x; 1.2841x over previous
//
#include <hip/hip_runtime.h>
#include <hip/hip_bf16.h>

#define B_   512
#define L_   64
#define D_   16
#define H_   256
#define V_   512
#define STEPS_ 64
#define DT_  0.984375f
#define LOSC 2048.0f          // lo-term scale 2^11
#define LOSC_INV (1.0f/2048.0f)

typedef _Float16 half_t;
typedef __attribute__((ext_vector_type(8))) _Float16 half8;
typedef __attribute__((ext_vector_type(4))) float f32x4;

__device__ __forceinline__ void split16(float x, half_t& hi, half_t& lo) {
    half_t h = (half_t)x;
    hi = h;
    lo = (half_t)((x - (float)h) * LOSC);
}

// ---------------- prep kernels ----------------

// Pack W [N][K] fp32 into MFMA B-fragment order, f16 hi + scaled-lo:
// slot idx = ((g*Kc + c)*64 + l)*8 + j  <-  W[g*16 + (l&15)][c*32 + (l>>4)*8 + j]
__global__ void pack_frag_kernel(const float* __restrict__ src, half_t* __restrict__ hi,
                                 half_t* __restrict__ lo, int Kc, int K, int total) {
    int idx = blockIdx.x * 256 + threadIdx.x;
    if (idx >= total) return;
    int j = idx & 7;
    int l = (idx >> 3) & 63;
    int gc = idx >> 9;
    int c = gc % Kc, g = gc / Kc;
    int n = (g << 4) + (l & 15);
    int k = (c << 5) + ((l >> 4) << 3) + j;
    float w = src[n * K + k];
    half_t h, lw;
    split16(w, h, lw);
    hi[idx] = h;
    lo[idx] = lw;
}

// h0 = tanh(X0 @ W0^T + b0)
__global__ void h0_kernel(const float* __restrict__ coeffs, const float* __restrict__ W0,
                          const float* __restrict__ b0, float* __restrict__ hout) {
    int b = blockIdx.x;
    int hh = threadIdx.x;
    float acc = b0[hh];
    #pragma unroll
    for (int d = 0; d < 16; d++)
        acc += coeffs[b * ((L_ - 1) * 4 * D_) + d] * W0[hh * 16 + d];
    hout[b * H_ + hh] = tanhf(acc);
}

// ---------------- per-step kernels ----------------

// GEMM1: t1 = tanh(h @ W1^T + b1) -> single-f16 A-fragments (Kc_out = 16).
// Grid (16,8), 512 threads; block = 32 rows x 64 cols.
__global__ __launch_bounds__(512) void gemm1_kernel(
    const float* __restrict__ hptr,
    const half_t* __restrict__ W1h, const half_t* __restrict__ W1l,
    const float* __restrict__ b1, half_t* __restrict__ t1)
{
    __shared__ __align__(16) half_t Ah[2 * 8 * 64 * 8];   // 16 KB
    __shared__ __align__(16) half_t Al[2 * 8 * 64 * 8];   // 16 KB
    __shared__ float zs[32][65];                          // 8.3 KB
    const int tid = threadIdx.x, w = tid >> 6, l = tid & 63;
    const int row0 = blockIdx.x * 32, col0 = blockIdx.y * 64;

    // stage h rows as f16 hi/lo fragments
    {
        int gm = w & 1;
        #pragma unroll
        for (int cc = 0; cc < 2; cc++) {
            int c = ((w >> 1) << 1) + cc;
            const float* src = hptr + (row0 + (gm << 4) + (l & 15)) * H_ + (c << 5) + ((l >> 4) << 3);
            float4 x = *(const float4*)src;
            float4 y = *(const float4*)(src + 4);
            float xx[8] = {x.x, x.y, x.z, x.w, y.x, y.y, y.z, y.w};
            half8 hv, lv;
            #pragma unroll
            for (int j = 0; j < 8; j++) { half_t a, b; split16(xx[j], a, b); hv[j] = a; lv[j] = b; }
            int base = (((gm << 3) + c) * 64 + l) * 8;
            *(half8*)&Ah[base] = hv;
            *(half8*)&Al[base] = lv;
        }
    }
    __syncthreads();

    const int mf = w & 1, nf = w >> 1;
    const int gn = (col0 >> 4) + nf;
    f32x4 acc = {0.f, 0.f, 0.f, 0.f}, accl = {0.f, 0.f, 0.f, 0.f};
    for (int c = 0; c < 8; c++) {
        half8 ah = *(const half8*)&Ah[(((mf << 3) + c) * 64 + l) * 8];
        half8 al = *(const half8*)&Al[(((mf << 3) + c) * 64 + l) * 8];
        half8 bh = *(const half8*)&W1h[(((gn << 3) + c) * 64 + l) * 8];
        half8 bl = *(const half8*)&W1l[(((gn << 3) + c) * 64 + l) * 8];
        acc  = __builtin_amdgcn_mfma_f32_16x16x32_f16(ah, bh, acc,  0, 0, 0);
        accl = __builtin_amdgcn_mfma_f32_16x16x32_f16(ah, bl, accl, 0, 0, 0);
        accl = __builtin_amdgcn_mfma_f32_16x16x32_f16(al, bh, accl, 0, 0, 0);
    }
    {
        int colb = (nf << 4) + (l & 15);
        float bb = b1[col0 + colb];
        #pragma unroll
        for (int j = 0; j < 4; j++) {
            float v = acc[j] + accl[j] * LOSC_INV + bb;
            zs[(mf << 4) + ((l >> 4) << 2) + j][colb] = tanhf(v);
        }
    }
    __syncthreads();
    // pack tanh output into single-f16 A-fragments for gemm2
    if (tid < 256) {
        int p = tid >> 6;              // (gm' 2) x (c' 2)
        int gmp = p & 1, cp = p >> 1;
        half8 hv;
        #pragma unroll
        for (int j = 0; j < 8; j++)
            hv[j] = (half_t)zs[(gmp << 4) + (l & 15)][(cp << 5) + ((l >> 4) << 3) + j];
        *(half8*)&t1[((((row0 >> 4) + gmp) * 16 + (col0 >> 5) + cp) * 64 + l) * 8] = hv;
    }
}

// GEMM2: t2 = tanh(LN1(t1) @ W2^T + b2) -> single-f16 fragments.
// LN1 stats computed in-block from the full-K rows it reads anyway.
// Grid (16,8), 512 threads; block = 32 rows x 64 cols.
__global__ __launch_bounds__(512) void gemm2_kernel(
    const half_t* __restrict__ t1,
    const float* __restrict__ g1, const float* __restrict__ be1,
    const half_t* __restrict__ W2h, const half_t* __restrict__ W2l,
    const float* __restrict__ b2, half_t* __restrict__ t2)
{
    __shared__ __align__(16) half_t Ah[2 * 16 * 64 * 8];  // 32 KB
    __shared__ __align__(16) half_t Al[2 * 16 * 64 * 8];  // 32 KB
    __shared__ float part[1024];                          // 4 KB
    __shared__ float mr[32], rrs[32];
    const int tid = threadIdx.x, w = tid >> 6, l = tid & 63;
    const int row0 = blockIdx.x * 32, col0 = blockIdx.y * 64;
    const int gm = w & 1, cbase = (w >> 1) << 2;

    // pass 1: read t1 (single f16), keep in regs, row stats
    float tv[32];
    {
        float s = 0.f, ss = 0.f;
        #pragma unroll
        for (int cc = 0; cc < 4; cc++) {
            int c = cbase + cc;
            int base = ((((row0 >> 4) + gm) * 16 + c) * 64 + l) * 8;
            half8 hv = *(const half8*)&t1[base];
            #pragma unroll
            for (int j = 0; j < 8; j++) {
                float t = (float)hv[j];
                tv[(cc << 3) + j] = t;
                s += t; ss += t * t;
            }
        }
        part[w * 64 + l] = s;
        part[512 + w * 64 + l] = ss;
    }
    __syncthreads();
    if (tid < 32) {
        int r = tid, rgm = r >> 4;
        float s = 0.f, ss = 0.f;
        #pragma unroll
        for (int wi = 0; wi < 4; wi++) {
            int wv = rgm + (wi << 1);
            #pragma unroll
            for (int u = 0; u < 4; u++) {
                int idx = wv * 64 + (r & 15) + (u << 4);
                s += part[idx]; ss += part[512 + idx];
            }
        }
        float m = s * (1.f / 512.f);
        float var = ss * (1.f / 512.f) - m * m;
        mr[r] = m;
        rrs[r] = rsqrtf(var + 1e-5f);
    }
    __syncthreads();
    // pass 2: normalize + hi/lo split into LDS fragments
    {
        int row = (gm << 4) + (l & 15);
        float m = mr[row], rv = rrs[row];
        #pragma unroll
        for (int cc = 0; cc < 4; cc++) {
            int c = cbase + cc;
            half8 hv, lv;
            #pragma unroll
            for (int j = 0; j < 8; j++) {
                int k = (c << 5) + ((l >> 4) << 3) + j;
                float val = (tv[(cc << 3) + j] - m) * rv * g1[k] + be1[k];
                half_t a, b; split16(val, a, b); hv[j] = a; lv[j] = b;
            }
            int base = (((gm << 4) + c) * 64 + l) * 8;
            *(half8*)&Ah[base] = hv;
            *(half8*)&Al[base] = lv;
        }
    }
    __syncthreads();

    const int mf = w & 1, nf = w >> 1;
    const int gn = (col0 >> 4) + nf;
    f32x4 acc = {0.f, 0.f, 0.f, 0.f}, accl = {0.f, 0.f, 0.f, 0.f};
    for (int c = 0; c < 16; c++) {
        half8 ah = *(const half8*)&Ah[(((mf << 4) + c) * 64 + l) * 8];
        half8 al = *(const half8*)&Al[(((mf << 4) + c) * 64 + l) * 8];
        half8 bh = *(const half8*)&W2h[(((gn << 4) + c) * 64 + l) * 8];
        half8 bl = *(const half8*)&W2l[(((gn << 4) + c) * 64 + l) * 8];
        acc  = __builtin_amdgcn_mfma_f32_16x16x32_f16(ah, bh, acc,  0, 0, 0);
        accl = __builtin_amdgcn_mfma_f32_16x16x32_f16(ah, bl, accl, 0, 0, 0);
        accl = __builtin_amdgcn_mfma_f32_16x16x32_f16(al, bh, accl, 0, 0, 0);
    }
    __syncthreads();                       // Ah reusable as zs
    float (*zs)[65] = (float(*)[65])Ah;
    {
        int colb = (nf << 4) + (l & 15);
        float bb = b2[col0 + colb];
        #pragma unroll
        for (int j = 0; j < 4; j++) {
            float v = acc[j] + accl[j] * LOSC_INV + bb;
            zs[(mf << 4) + ((l >> 4) << 2) + j][colb] = tanhf(v);
        }
    }
    __syncthreads();
    if (tid < 256) {
        int p = tid >> 6;
        int gmp = p & 1, cp = p >> 1;
        half8 hv;
        #pragma unroll
        for (int j = 0; j < 8; j++)
            hv[j] = (half_t)zs[(gmp << 4) + (l & 15)][(cp << 5) + ((l >> 4) << 3) + j];
        *(half8*)&t2[((((row0 >> 4) + gmp) * 16 + (col0 >> 5) + cp) * 64 + l) * 8] = hv;
    }
}

// Stage 3: vf = LN2(t2) @ W3^T + b3; h += dt*(vf . dX).
// 256 blocks = 8 row-groups (64 rows) x 32 col-groups (128 cols).
// Wave w owns n-group gn = cg*8 + w (== hh); 4 m-frags.
__global__ __launch_bounds__(512) void stage3_kernel(
    const half_t* __restrict__ t2, const half_t* __restrict__ W3h,
    const float* __restrict__ g2, const float* __restrict__ be2,
    const float* __restrict__ b3, const float* __restrict__ coeffs,
    float* __restrict__ hbuf, int ii, float frac)
{
    __shared__ __align__(16) half_t Ah[4 * 16 * 64 * 8];  // 64 KB
    __shared__ float dxs[64][17];                          // 4.25 KB
    __shared__ float part[256];                            // [s|ss][w*16+r]
    __shared__ float mr[64], rrs[64];
    const int tid = threadIdx.x, w = tid >> 6, l = tid & 63;
    const int rg = blockIdx.x >> 5;      // 0..7
    const int cg = blockIdx.x & 31;      // 0..31
    const int row0 = rg << 6;
    const int gn = (cg << 3) + w;
    const int gm = w >> 1, kh = w & 1;   // wave's m-group (0..3) and k-half

    // spline derivative for the block's 64 rows
    for (int idx = tid; idx < 64 * 16; idx += 512) {
        int r = idx >> 4, d = idx & 15;
        int base = ((row0 + r) * (L_ - 1) + ii) * 64 + d;
        float c1 = coeffs[base + 16], c2 = coeffs[base + 32], c3 = coeffs[base + 48];
        dxs[r][d] = c1 + 2.0f * frac * c2 + 3.0f * (frac * frac) * c3;
    }

    // pass 1: stage raw t2 frags into LDS + row stats (LN2 over K=512)
    {
        float s = 0.f, ss = 0.f;
        #pragma unroll
        for (int cc = 0; cc < 8; cc++) {
            int c = (kh << 3) + cc;
            half8 hv = *(const half8*)&t2[((((rg << 2) + gm) * 16 + c) * 64 + l) * 8];
            *(half8*)&Ah[(((gm << 4) + c) * 64 + l) * 8] = hv;
            #pragma unroll
            for (int j = 0; j < 8; j++) { float t = (float)hv[j]; s += t; ss += t * t; }
        }
        s  += __shfl_xor(s, 16);  s  += __shfl_xor(s, 32);
        ss += __shfl_xor(ss, 16); ss += __shfl_xor(ss, 32);
        if (l < 16) { part[w * 16 + l] = s; part[128 + w * 16 + l] = ss; }
    }
    __syncthreads();
    if (tid < 64) {
        int r = tid;
        int w0 = (r >> 4) << 1, rl = r & 15;
        float s  = part[w0 * 16 + rl] + part[(w0 + 1) * 16 + rl];
        float ss = part[128 + w0 * 16 + rl] + part[128 + (w0 + 1) * 16 + rl];
        float m = s * (1.f / 512.f);
        mr[r] = m;
        rrs[r] = rsqrtf(ss * (1.f / 512.f) - m * m + 1e-5f);
    }
    __syncthreads();
    // pass 2: normalize in place (f16)
    {
        int r = (gm << 4) + (l & 15);
        float m = mr[r], rv = rrs[r];
        #pragma unroll
        for (int cc = 0; cc < 8; cc++) {
            int c = (kh << 3) + cc;
            int lb = (((gm << 4) + c) * 64 + l) * 8;
            half8 hv = *(const half8*)&Ah[lb];
            int k0 = (c << 5) + ((l >> 4) << 3);
            float4 ga = *(const float4*)&g2[k0];
            float4 gb = *(const float4*)&g2[k0 + 4];
            float4 ba = *(const float4*)&be2[k0];
            float4 bb = *(const float4*)&be2[k0 + 4];
            float gv[8] = {ga.x, ga.y, ga.z, ga.w, gb.x, gb.y, gb.z, gb.w};
            float bv[8] = {ba.x, ba.y, ba.z, ba.w, bb.x, bb.y, bb.z, bb.w};
            half8 ov;
            #pragma unroll
            for (int j = 0; j < 8; j++)
                ov[j] = (half_t)(((float)hv[j] - m) * rv * gv[j] + bv[j]);
            *(half8*)&Ah[lb] = ov;
        }
    }
    __syncthreads();

    f32x4 acc[4];
    #pragma unroll
    for (int i = 0; i < 4; i++) acc[i] = (f32x4){0, 0, 0, 0};
    for (int c = 0; c < 16; c++) {
        half8 bh = *(const half8*)&W3h[(((gn << 4) + c) * 64 + l) * 8];
        #pragma unroll
        for (int mf = 0; mf < 4; mf++) {
            half8 ah = *(const half8*)&Ah[(((mf << 4) + c) * 64 + l) * 8];
            acc[mf] = __builtin_amdgcn_mfma_f32_16x16x32_f16(ah, bh, acc[mf], 0, 0, 0);
        }
    }

    // epilogue: + b3, contract with dX over d=l&15, 16-lane reduce, unique-writer h RMW
    const int d = l & 15;
    const float b3v = b3[(gn << 4) + d];
    #pragma unroll
    for (int mf = 0; mf < 4; mf++) {
        #pragma unroll
        for (int j = 0; j < 4; j++) {
            int rl = (mf << 4) + ((l >> 4) << 2) + j;
            float s = (acc[mf][j] + b3v) * dxs[rl][d];
            s += __shfl_xor(s, 1);
            s += __shfl_xor(s, 2);
            s += __shfl_xor(s, 4);
            s += __shfl_xor(s, 8);
            if (d == 0) hbuf[(row0 + rl) * H_ + gn] += s * DT_;
        }
    }
}

// ---------------- launch ----------------

extern "C" void kernel_launch(void* const* d_in, const int* in_sizes, int n_in,
                              void* d_out, int out_size, void* d_ws, size_t ws_size,
                              hipStream_t stream) {
    const float* coeffs = (const float*)d_in[0];
    const float* W0  = (const float*)d_in[1];
    const float* b0  = (const float*)d_in[2];
    const float* W1  = (const float*)d_in[3];
    const float* b1  = (const float*)d_in[4];
    const float* g1  = (const float*)d_in[5];
    const float* be1 = (const float*)d_in[6];
    const float* W2  = (const float*)d_in[7];
    const float* b2  = (const float*)d_in[8];
    const float* g2  = (const float*)d_in[9];
    const float* be2 = (const float*)d_in[10];
    const float* W3  = (const float*)d_in[11];
    const float* b3  = (const float*)d_in[12];

    char* w = (char*)d_ws;
    float*  hbuf = (float*)(w);                        // 512 KB
    half_t* t1   = (half_t*)(w + 524288);              // 512 KB
    half_t* t2   = (half_t*)(w + 1048576);             // 512 KB
    half_t* W1h  = (half_t*)(w + 1572864);             // 256 KB
    half_t* W1l  = (half_t*)(w + 1835008);             // 256 KB
    half_t* W2h  = (half_t*)(w + 2097152);             // 512 KB
    half_t* W2l  = (half_t*)(w + 2621440);             // 512 KB
    half_t* W3h  = (half_t*)(w + 3145728);             // 4 MB
    half_t* W3l  = (half_t*)(w + 7340032);             // 4 MB (packed, unused)

    pack_frag_kernel<<<512, 256, 0, stream>>>(W1, W1h, W1l, 8, H_, V_ * H_);
    pack_frag_kernel<<<1024, 256, 0, stream>>>(W2, W2h, W2l, 16, V_, V_ * V_);
    pack_frag_kernel<<<8192, 256, 0, stream>>>(W3, W3h, W3l, 16, V_, (H_ * D_) * V_);
    h0_kernel<<<B_, H_, 0, stream>>>(coeffs, W0, b0, hbuf);

    for (int s = 0; s < STEPS_; s++) {
        float t = (float)s * 0.984375f;      // exact in fp32
        int ii = (int)t;
        if (ii > L_ - 2) ii = L_ - 2;
        float frac = t - (float)ii;
        gemm1_kernel<<<dim3(16, 8), 512, 0, stream>>>(hbuf, W1h, W1l, b1, t1);
        gemm2_kernel<<<dim3(16, 8), 512, 0, stream>>>(t1, g1, be1, W2h, W2l, b2, t2);
        stage3_kernel<<<256, 512, 0, stream>>>(t2, W3h, g2, be2, b3, coeffs,
                                               hbuf, ii, frac);
    }

    hipMemcpyAsync(d_out, hbuf, (size_t)B_ * H_ * sizeof(float),
                   hipMemcpyDeviceToDevice, stream);
}

// Round 9
// 1519.545 us; speedup vs baseline: 4.5248x; 1.1176x over previous
//
#include <hip/hip_runtime.h>
#include <hip/hip_bf16.h>

#define B_   512
#define L_   64
#define D_   16
#define H_   256
#define V_   512
#define STEPS_ 64
#define DT_  0.984375f
#define LOSC 2048.0f          // lo-term scale 2^11
#define LOSC_INV (1.0f/2048.0f)

typedef _Float16 half_t;
typedef __attribute__((ext_vector_type(8))) _Float16 half8;
typedef __attribute__((ext_vector_type(4))) float f32x4;

__device__ __forceinline__ void split16(float x, half_t& hi, half_t& lo) {
    half_t h = (half_t)x;
    hi = h;
    lo = (half_t)((x - (float)h) * LOSC);
}

// ---------------- prep kernels ----------------

// Pack W [N][K] fp32 into MFMA B-fragment order, f16 hi + scaled-lo:
// slot idx = ((g*Kc + c)*64 + l)*8 + j  <-  W[g*16 + (l&15)][c*32 + (l>>4)*8 + j]
__global__ void pack_frag_kernel(const float* __restrict__ src, half_t* __restrict__ hi,
                                 half_t* __restrict__ lo, int Kc, int K, int total) {
    int idx = blockIdx.x * 256 + threadIdx.x;
    if (idx >= total) return;
    int j = idx & 7;
    int l = (idx >> 3) & 63;
    int gc = idx >> 9;
    int c = gc % Kc, g = gc / Kc;
    int n = (g << 4) + (l & 15);
    int k = (c << 5) + ((l >> 4) << 3) + j;
    float w = src[n * K + k];
    half_t h, lw;
    split16(w, h, lw);
    hi[idx] = h;
    lo[idx] = lw;
}

// Same, but W pre-scaled by per-k vector (g folded in); hi/lo outputs.
__global__ void pack_frag_scaled2_kernel(const float* __restrict__ src,
                                         const float* __restrict__ scale,
                                         half_t* __restrict__ hi, half_t* __restrict__ lo,
                                         int Kc, int K, int total) {
    int idx = blockIdx.x * 256 + threadIdx.x;
    if (idx >= total) return;
    int j = idx & 7;
    int l = (idx >> 3) & 63;
    int gc = idx >> 9;
    int c = gc % Kc, g = gc / Kc;
    int n = (g << 4) + (l & 15);
    int k = (c << 5) + ((l >> 4) << 3) + j;
    float w = src[n * K + k] * scale[k];
    half_t h, lw;
    split16(w, h, lw);
    hi[idx] = h;
    lo[idx] = lw;
}

// Scaled, hi only (for W3g).
__global__ void pack_frag_scaled1_kernel(const float* __restrict__ src,
                                         const float* __restrict__ scale,
                                         half_t* __restrict__ hi,
                                         int Kc, int K, int total) {
    int idx = blockIdx.x * 256 + threadIdx.x;
    if (idx >= total) return;
    int j = idx & 7;
    int l = (idx >> 3) & 63;
    int gc = idx >> 9;
    int c = gc % Kc, g = gc / Kc;
    int n = (g << 4) + (l & 15);
    int k = (c << 5) + ((l >> 4) << 3) + j;
    hi[idx] = (half_t)(src[n * K + k] * scale[k]);
}

// cg[n] = sum_k g[k]*W[n,k];  cb[n] = sum_k be[k]*W[n,k] + b[n]
__global__ void colvec_kernel(const float* __restrict__ W, const float* __restrict__ g,
                              const float* __restrict__ be, const float* __restrict__ b,
                              float* __restrict__ cg, float* __restrict__ cb, int N, int K) {
    int n = blockIdx.x * 4 + (threadIdx.x >> 6);
    if (n >= N) return;
    int l = threadIdx.x & 63;
    float sg = 0.f, sb = 0.f;
    for (int k = l; k < K; k += 64) {
        float w = W[n * K + k];
        sg += g[k] * w;
        sb += be[k] * w;
    }
    #pragma unroll
    for (int o = 32; o; o >>= 1) { sg += __shfl_xor(sg, o); sb += __shfl_xor(sb, o); }
    if (l == 0) { cg[n] = sg; cb[n] = sb + b[n]; }
}

// h0 = tanh(X0 @ W0^T + b0)
__global__ void h0_kernel(const float* __restrict__ coeffs, const float* __restrict__ W0,
                          const float* __restrict__ b0, float* __restrict__ hout) {
    int b = blockIdx.x;
    int hh = threadIdx.x;
    float acc = b0[hh];
    #pragma unroll
    for (int d = 0; d < 16; d++)
        acc += coeffs[b * ((L_ - 1) * 4 * D_) + d] * W0[hh * 16 + d];
    hout[b * H_ + hh] = tanhf(acc);
}

// ---------------- per-step kernels ----------------

// GEMM1: t1 = tanh(h @ W1^T + b1) -> single-f16 A-fragments + per-block row stats.
// Grid (16,8), 512 threads; block = 32 rows x 64 cols.
__global__ __launch_bounds__(512) void gemm1_kernel(
    const float* __restrict__ hptr,
    const half_t* __restrict__ W1h, const half_t* __restrict__ W1l,
    const float* __restrict__ b1, half_t* __restrict__ t1,
    float* __restrict__ stats1, int sIdx)
{
    __shared__ __align__(16) half_t Ah[2 * 8 * 64 * 8];   // 16 KB
    __shared__ __align__(16) half_t Al[2 * 8 * 64 * 8];   // 16 KB
    __shared__ float zs[32][65];                          // 8.3 KB
    const int tid = threadIdx.x, w = tid >> 6, l = tid & 63;
    const int row0 = blockIdx.x * 32, col0 = blockIdx.y * 64;

    // stage h rows as f16 hi/lo fragments
    {
        int gm = w & 1;
        #pragma unroll
        for (int cc = 0; cc < 2; cc++) {
            int c = ((w >> 1) << 1) + cc;
            const float* src = hptr + (row0 + (gm << 4) + (l & 15)) * H_ + (c << 5) + ((l >> 4) << 3);
            float4 x = *(const float4*)src;
            float4 y = *(const float4*)(src + 4);
            float xx[8] = {x.x, x.y, x.z, x.w, y.x, y.y, y.z, y.w};
            half8 hv, lv;
            #pragma unroll
            for (int j = 0; j < 8; j++) { half_t a, b; split16(xx[j], a, b); hv[j] = a; lv[j] = b; }
            int base = (((gm << 3) + c) * 64 + l) * 8;
            *(half8*)&Ah[base] = hv;
            *(half8*)&Al[base] = lv;
        }
    }
    __syncthreads();

    const int mf = w & 1, nf = w >> 1;
    const int gn = (col0 >> 4) + nf;
    f32x4 acc = {0.f, 0.f, 0.f, 0.f}, accl = {0.f, 0.f, 0.f, 0.f};
    for (int c = 0; c < 8; c++) {
        half8 ah = *(const half8*)&Ah[(((mf << 3) + c) * 64 + l) * 8];
        half8 al = *(const half8*)&Al[(((mf << 3) + c) * 64 + l) * 8];
        half8 bh = *(const half8*)&W1h[(((gn << 3) + c) * 64 + l) * 8];
        half8 bl = *(const half8*)&W1l[(((gn << 3) + c) * 64 + l) * 8];
        acc  = __builtin_amdgcn_mfma_f32_16x16x32_f16(ah, bh, acc,  0, 0, 0);
        accl = __builtin_amdgcn_mfma_f32_16x16x32_f16(ah, bl, accl, 0, 0, 0);
        accl = __builtin_amdgcn_mfma_f32_16x16x32_f16(al, bh, accl, 0, 0, 0);
    }
    {
        int colb = (nf << 4) + (l & 15);
        float bb = b1[col0 + colb];
        #pragma unroll
        for (int j = 0; j < 4; j++) {
            float v = acc[j] + accl[j] * LOSC_INV + bb;
            zs[(mf << 4) + ((l >> 4) << 2) + j][colb] = tanhf(v);
        }
    }
    __syncthreads();
    // per-block row stats over the 64 local cols -> unique slot (no atomics)
    {
        int r = tid >> 4, c0 = (tid & 15) << 2;
        float s = 0.f, ss = 0.f;
        #pragma unroll
        for (int j = 0; j < 4; j++) { float v = zs[r][c0 + j]; s += v; ss += v * v; }
        #pragma unroll
        for (int o = 8; o; o >>= 1) { s += __shfl_xor(s, o); ss += __shfl_xor(ss, o); }
        if ((tid & 15) == 0) {
            float* st = stats1 + (((sIdx << 3) + blockIdx.y) * 512 + row0 + r) * 2;
            st[0] = s; st[1] = ss;
        }
    }
    // pack tanh output into single-f16 A-fragments for gemm2
    if (tid < 256) {
        int p = tid >> 6;              // (gm' 2) x (c' 2)
        int gmp = p & 1, cp = p >> 1;
        half8 hv;
        #pragma unroll
        for (int j = 0; j < 8; j++)
            hv[j] = (half_t)zs[(gmp << 4) + (l & 15)][(cp << 5) + ((l >> 4) << 3) + j];
        *(half8*)&t1[((((row0 >> 4) + gmp) * 16 + (col0 >> 5) + cp) * 64 + l) * 8] = hv;
    }
}

// GEMM2: t2 = tanh(rv*(t1 @ W2g^T) - m*rv*cg2 + cb2) -> single-f16 fragments + stats.
// LN folded: W2g = g1*W2 (hi/lo), cg2/cb2 precomputed. Raw t1 frags read from L2.
// Grid (16,8), 512 threads; block = 32 rows x 64 cols.
__global__ __launch_bounds__(512) void gemm2_kernel(
    const half_t* __restrict__ t1, const float* __restrict__ stats1,
    const half_t* __restrict__ W2gh, const half_t* __restrict__ W2gl,
    const float* __restrict__ cg2, const float* __restrict__ cb2,
    half_t* __restrict__ t2, float* __restrict__ stats2, int sIdx)
{
    __shared__ float zs[32][65];
    __shared__ float mr[32], rrs[32];
    const int tid = threadIdx.x, w = tid >> 6, l = tid & 63;
    const int row0 = blockIdx.x * 32, col0 = blockIdx.y * 64;

    // prologue: finalize LN1 stats for our 32 rows
    if (tid < 32) {
        float s = 0.f, ss = 0.f;
        #pragma unroll
        for (int p = 0; p < 8; p++) {
            const float* st = stats1 + (((sIdx << 3) + p) * 512 + row0 + tid) * 2;
            s += st[0]; ss += st[1];
        }
        float m = s * (1.f / 512.f);
        mr[tid] = m;
        rrs[tid] = rsqrtf(ss * (1.f / 512.f) - m * m + 1e-5f);
    }
    __syncthreads();

    const int mf = w & 1, nf = w >> 1;
    const int gn = (col0 >> 4) + nf;
    const int gmA = (row0 >> 4) + mf;
    f32x4 acc = {0.f, 0.f, 0.f, 0.f}, accl = {0.f, 0.f, 0.f, 0.f};
    for (int c = 0; c < 16; c++) {
        half8 ah = *(const half8*)&t1[((gmA * 16 + c) * 64 + l) * 8];
        half8 bh = *(const half8*)&W2gh[(((gn << 4) + c) * 64 + l) * 8];
        half8 bl = *(const half8*)&W2gl[(((gn << 4) + c) * 64 + l) * 8];
        acc  = __builtin_amdgcn_mfma_f32_16x16x32_f16(ah, bh, acc,  0, 0, 0);
        accl = __builtin_amdgcn_mfma_f32_16x16x32_f16(ah, bl, accl, 0, 0, 0);
    }
    {
        int colb = (nf << 4) + (l & 15);
        int col = col0 + colb;
        float cgv = cg2[col], cbv = cb2[col];
        #pragma unroll
        for (int j = 0; j < 4; j++) {
            int r = (mf << 4) + ((l >> 4) << 2) + j;
            float S = acc[j] + accl[j] * LOSC_INV;
            float v = rrs[r] * S - mr[r] * rrs[r] * cgv + cbv;
            zs[r][colb] = tanhf(v);
        }
    }
    __syncthreads();
    // stats epilogue (LN2 partials)
    {
        int r = tid >> 4, c0 = (tid & 15) << 2;
        float s = 0.f, ss = 0.f;
        #pragma unroll
        for (int j = 0; j < 4; j++) { float v = zs[r][c0 + j]; s += v; ss += v * v; }
        #pragma unroll
        for (int o = 8; o; o >>= 1) { s += __shfl_xor(s, o); ss += __shfl_xor(ss, o); }
        if ((tid & 15) == 0) {
            float* st = stats2 + (((sIdx << 3) + blockIdx.y) * 512 + row0 + r) * 2;
            st[0] = s; st[1] = ss;
        }
    }
    // pack t2 single-f16 frags
    if (tid < 256) {
        int p = tid >> 6;
        int gmp = p & 1, cp = p >> 1;
        half8 hv;
        #pragma unroll
        for (int j = 0; j < 8; j++)
            hv[j] = (half_t)zs[(gmp << 4) + (l & 15)][(cp << 5) + ((l >> 4) << 3) + j];
        *(half8*)&t2[((((row0 >> 4) + gmp) * 16 + (col0 >> 5) + cp) * 64 + l) * 8] = hv;
    }
}

// Stage 3: vf = rv2*(t2 @ W3g^T) - m2*rv2*cg3 + cb3;  h += dt*(vf . dX).
// 256 blocks = 8 row-groups (64 rows) x 32 col-groups (128 cols).
// Wave w owns n-group gn = cg*8 + w (== hh); 4 m-frags.
__global__ __launch_bounds__(512) void stage3_kernel(
    const half_t* __restrict__ t2, const float* __restrict__ stats2,
    const half_t* __restrict__ W3gh, const float* __restrict__ cg3,
    const float* __restrict__ cb3, const float* __restrict__ coeffs,
    float* __restrict__ hbuf, int ii, float frac, int sIdx)
{
    __shared__ __align__(16) half_t Ah[4 * 16 * 64 * 8];  // 64 KB
    __shared__ float dxs[64][17];                          // 4.25 KB
    __shared__ float mvals[64], rvals[64];
    const int tid = threadIdx.x, w = tid >> 6, l = tid & 63;
    const int rg = blockIdx.x >> 5;      // 0..7
    const int cgi = blockIdx.x & 31;     // 0..31
    const int row0 = rg << 6;
    const int gn = (cgi << 3) + w;
    const int gm = w >> 1, kh = w & 1;

    // spline derivative for the block's 64 rows
    for (int idx = tid; idx < 64 * 16; idx += 512) {
        int r = idx >> 4, d = idx & 15;
        int base = ((row0 + r) * (L_ - 1) + ii) * 64 + d;
        float c1 = coeffs[base + 16], c2 = coeffs[base + 32], c3 = coeffs[base + 48];
        dxs[r][d] = c1 + 2.0f * frac * c2 + 3.0f * (frac * frac) * c3;
    }
    // finalize LN2 stats for 64 rows
    if (tid < 64) {
        float s = 0.f, ss = 0.f;
        #pragma unroll
        for (int p = 0; p < 8; p++) {
            const float* st = stats2 + (((sIdx << 3) + p) * 512 + row0 + tid) * 2;
            s += st[0]; ss += st[1];
        }
        float m = s * (1.f / 512.f);
        mvals[tid] = m;
        rvals[tid] = rsqrtf(ss * (1.f / 512.f) - m * m + 1e-5f);
    }
    // stage raw t2 frags into LDS (64 KB)
    #pragma unroll
    for (int cc = 0; cc < 8; cc++) {
        int c = (kh << 3) + cc;
        half8 hv = *(const half8*)&t2[((((rg << 2) + gm) * 16 + c) * 64 + l) * 8];
        *(half8*)&Ah[(((gm << 4) + c) * 64 + l) * 8] = hv;
    }
    __syncthreads();

    f32x4 acc[4];
    #pragma unroll
    for (int i = 0; i < 4; i++) acc[i] = (f32x4){0, 0, 0, 0};
    for (int c = 0; c < 16; c++) {
        half8 bh = *(const half8*)&W3gh[(((gn << 4) + c) * 64 + l) * 8];
        #pragma unroll
        for (int mf = 0; mf < 4; mf++) {
            half8 ah = *(const half8*)&Ah[(((mf << 4) + c) * 64 + l) * 8];
            acc[mf] = __builtin_amdgcn_mfma_f32_16x16x32_f16(ah, bh, acc[mf], 0, 0, 0);
        }
    }

    // epilogue: affine LN fix + dX contraction + unique-writer h RMW
    const int d = l & 15;
    const int o = (gn << 4) + d;
    const float cgv = cg3[o], cbv = cb3[o];
    #pragma unroll
    for (int mf = 0; mf < 4; mf++) {
        #pragma unroll
        for (int j = 0; j < 4; j++) {
            int rl = (mf << 4) + ((l >> 4) << 2) + j;
            float vf = rvals[rl] * acc[mf][j] - mvals[rl] * rvals[rl] * cgv + cbv;
            float s = vf * dxs[rl][d];
            s += __shfl_xor(s, 1);
            s += __shfl_xor(s, 2);
            s += __shfl_xor(s, 4);
            s += __shfl_xor(s, 8);
            if (d == 0) hbuf[(row0 + rl) * H_ + gn] += s * DT_;
        }
    }
}

// ---------------- launch ----------------

extern "C" void kernel_launch(void* const* d_in, const int* in_sizes, int n_in,
                              void* d_out, int out_size, void* d_ws, size_t ws_size,
                              hipStream_t stream) {
    const float* coeffs = (const float*)d_in[0];
    const float* W0  = (const float*)d_in[1];
    const float* b0  = (const float*)d_in[2];
    const float* W1  = (const float*)d_in[3];
    const float* b1  = (const float*)d_in[4];
    const float* g1  = (const float*)d_in[5];
    const float* be1 = (const float*)d_in[6];
    const float* W2  = (const float*)d_in[7];
    const float* b2  = (const float*)d_in[8];
    const float* g2  = (const float*)d_in[9];
    const float* be2 = (const float*)d_in[10];
    const float* W3  = (const float*)d_in[11];
    const float* b3  = (const float*)d_in[12];

    char* w = (char*)d_ws;
    float*  hbuf   = (float*)(w);                      // 512 KB
    half_t* t1     = (half_t*)(w + 524288);            // 512 KB
    half_t* t2     = (half_t*)(w + 1048576);           // 512 KB
    half_t* W1h    = (half_t*)(w + 1572864);           // 256 KB
    half_t* W1l    = (half_t*)(w + 1835008);           // 256 KB
    half_t* W2gh   = (half_t*)(w + 2097152);           // 512 KB
    half_t* W2gl   = (half_t*)(w + 2621440);           // 512 KB
    half_t* W3gh   = (half_t*)(w + 3145728);           // 4 MB
    float*  cg2    = (float*)(w + 7340032);            // 2 KB
    float*  cb2    = (float*)(w + 7342080);            // 2 KB
    float*  cg3    = (float*)(w + 7344128);            // 16 KB
    float*  cb3    = (float*)(w + 7360512);            // 16 KB
    float*  stats1 = (float*)(w + 7376896);            // 2 MB
    float*  stats2 = (float*)(w + 9474048);            // 2 MB   (ends ~11.6 MB)

    pack_frag_kernel<<<512, 256, 0, stream>>>(W1, W1h, W1l, 8, H_, V_ * H_);
    pack_frag_scaled2_kernel<<<1024, 256, 0, stream>>>(W2, g1, W2gh, W2gl, 16, V_, V_ * V_);
    pack_frag_scaled1_kernel<<<8192, 256, 0, stream>>>(W3, g2, W3gh, 16, V_, (H_ * D_) * V_);
    colvec_kernel<<<V_ / 4, 256, 0, stream>>>(W2, g1, be1, b2, cg2, cb2, V_, V_);
    colvec_kernel<<<(H_ * D_) / 4, 256, 0, stream>>>(W3, g2, be2, b3, cg3, cb3, H_ * D_, V_);
    h0_kernel<<<B_, H_, 0, stream>>>(coeffs, W0, b0, hbuf);

    for (int s = 0; s < STEPS_; s++) {
        float t = (float)s * 0.984375f;      // exact in fp32
        int ii = (int)t;
        if (ii > L_ - 2) ii = L_ - 2;
        float frac = t - (float)ii;
        gemm1_kernel<<<dim3(16, 8), 512, 0, stream>>>(hbuf, W1h, W1l, b1, t1, stats1, s);
        gemm2_kernel<<<dim3(16, 8), 512, 0, stream>>>(t1, stats1, W2gh, W2gl,
                                                      cg2, cb2, t2, stats2, s);
        stage3_kernel<<<256, 512, 0, stream>>>(t2, stats2, W3gh, cg3, cb3, coeffs,
                                               hbuf, ii, frac, s);
    }

    hipMemcpyAsync(d_out, hbuf, (size_t)B_ * H_ * sizeof(float),
                   hipMemcpyDeviceToDevice, stream);
}

// Round 10
// 1513.762 us; speedup vs baseline: 4.5421x; 1.0038x over previous
//
#include <hip/hip_runtime.h>
#include <hip/hip_bf16.h>

#define B_   512
#define L_   64
#define D_   16
#define H_   256
#define V_   512
#define STEPS_ 64
#define DT_  0.984375f
#define LOSC 2048.0f          // lo-term scale 2^11
#define LOSC_INV (1.0f/2048.0f)

typedef _Float16 half_t;
typedef __attribute__((ext_vector_type(8))) _Float16 half8;
typedef __attribute__((ext_vector_type(4))) float f32x4;

__device__ __forceinline__ void split16(float x, half_t& hi, half_t& lo) {
    half_t h = (half_t)x;
    hi = h;
    lo = (half_t)((x - (float)h) * LOSC);
}

// ---------------- prep kernels ----------------

// Pack W [N][K] fp32 into MFMA B-fragment order, f16 hi + scaled-lo:
// slot idx = ((g*Kc + c)*64 + l)*8 + j  <-  W[g*16 + (l&15)][c*32 + (l>>4)*8 + j]
__global__ void pack_frag_kernel(const float* __restrict__ src, half_t* __restrict__ hi,
                                 half_t* __restrict__ lo, int Kc, int K, int total) {
    int idx = blockIdx.x * 256 + threadIdx.x;
    if (idx >= total) return;
    int j = idx & 7;
    int l = (idx >> 3) & 63;
    int gc = idx >> 9;
    int c = gc % Kc, g = gc / Kc;
    int n = (g << 4) + (l & 15);
    int k = (c << 5) + ((l >> 4) << 3) + j;
    float w = src[n * K + k];
    half_t h, lw;
    split16(w, h, lw);
    hi[idx] = h;
    lo[idx] = lw;
}

// Same, but W pre-scaled by per-k vector (g folded in); hi/lo outputs.
__global__ void pack_frag_scaled2_kernel(const float* __restrict__ src,
                                         const float* __restrict__ scale,
                                         half_t* __restrict__ hi, half_t* __restrict__ lo,
                                         int Kc, int K, int total) {
    int idx = blockIdx.x * 256 + threadIdx.x;
    if (idx >= total) return;
    int j = idx & 7;
    int l = (idx >> 3) & 63;
    int gc = idx >> 9;
    int c = gc % Kc, g = gc / Kc;
    int n = (g << 4) + (l & 15);
    int k = (c << 5) + ((l >> 4) << 3) + j;
    float w = src[n * K + k] * scale[k];
    half_t h, lw;
    split16(w, h, lw);
    hi[idx] = h;
    lo[idx] = lw;
}

// Scaled, hi only (for W3g).
__global__ void pack_frag_scaled1_kernel(const float* __restrict__ src,
                                         const float* __restrict__ scale,
                                         half_t* __restrict__ hi,
                                         int Kc, int K, int total) {
    int idx = blockIdx.x * 256 + threadIdx.x;
    if (idx >= total) return;
    int j = idx & 7;
    int l = (idx >> 3) & 63;
    int gc = idx >> 9;
    int c = gc % Kc, g = gc / Kc;
    int n = (g << 4) + (l & 15);
    int k = (c << 5) + ((l >> 4) << 3) + j;
    hi[idx] = (half_t)(src[n * K + k] * scale[k]);
}

// cg[n] = sum_k g[k]*W[n,k];  cb[n] = sum_k be[k]*W[n,k] + b[n]
__global__ void colvec_kernel(const float* __restrict__ W, const float* __restrict__ g,
                              const float* __restrict__ be, const float* __restrict__ b,
                              float* __restrict__ cg, float* __restrict__ cb, int N, int K) {
    int n = blockIdx.x * 4 + (threadIdx.x >> 6);
    if (n >= N) return;
    int l = threadIdx.x & 63;
    float sg = 0.f, sb = 0.f;
    for (int k = l; k < K; k += 64) {
        float w = W[n * K + k];
        sg += g[k] * w;
        sb += be[k] * w;
    }
    #pragma unroll
    for (int o = 32; o; o >>= 1) { sg += __shfl_xor(sg, o); sb += __shfl_xor(sb, o); }
    if (l == 0) { cg[n] = sg; cb[n] = sb + b[n]; }
}

// h0 = tanh(X0 @ W0^T + b0)
__global__ void h0_kernel(const float* __restrict__ coeffs, const float* __restrict__ W0,
                          const float* __restrict__ b0, float* __restrict__ hout) {
    int b = blockIdx.x;
    int hh = threadIdx.x;
    float acc = b0[hh];
    #pragma unroll
    for (int d = 0; d < 16; d++)
        acc += coeffs[b * ((L_ - 1) * 4 * D_) + d] * W0[hh * 16 + d];
    hout[b * H_ + hh] = tanhf(acc);
}

// ---------------- per-step kernels ----------------

// GEMM1: t1 = tanh(h @ W1^T + b1) -> single-f16 A-fragments + per-block row stats.
// Grid (16,8), 512 threads; block = 32 rows x 64 cols.
__global__ __launch_bounds__(512) void gemm1_kernel(
    const float* __restrict__ hptr,
    const half_t* __restrict__ W1h, const half_t* __restrict__ W1l,
    const float* __restrict__ b1, half_t* __restrict__ t1,
    float* __restrict__ stats1, int sIdx)
{
    __shared__ __align__(16) half_t Ah[2 * 8 * 64 * 8];   // 16 KB
    __shared__ __align__(16) half_t Al[2 * 8 * 64 * 8];   // 16 KB
    __shared__ float zs[32][65];                          // 8.3 KB
    const int tid = threadIdx.x, w = tid >> 6, l = tid & 63;
    const int row0 = blockIdx.x * 32, col0 = blockIdx.y * 64;

    // stage h rows as f16 hi/lo fragments
    {
        int gm = w & 1;
        #pragma unroll
        for (int cc = 0; cc < 2; cc++) {
            int c = ((w >> 1) << 1) + cc;
            const float* src = hptr + (row0 + (gm << 4) + (l & 15)) * H_ + (c << 5) + ((l >> 4) << 3);
            float4 x = *(const float4*)src;
            float4 y = *(const float4*)(src + 4);
            float xx[8] = {x.x, x.y, x.z, x.w, y.x, y.y, y.z, y.w};
            half8 hv, lv;
            #pragma unroll
            for (int j = 0; j < 8; j++) { half_t a, b; split16(xx[j], a, b); hv[j] = a; lv[j] = b; }
            int base = (((gm << 3) + c) * 64 + l) * 8;
            *(half8*)&Ah[base] = hv;
            *(half8*)&Al[base] = lv;
        }
    }
    __syncthreads();

    const int mf = w & 1, nf = w >> 1;
    const int gn = (col0 >> 4) + nf;
    f32x4 acc = {0.f, 0.f, 0.f, 0.f}, accl = {0.f, 0.f, 0.f, 0.f};
    for (int c = 0; c < 8; c++) {
        half8 ah = *(const half8*)&Ah[(((mf << 3) + c) * 64 + l) * 8];
        half8 al = *(const half8*)&Al[(((mf << 3) + c) * 64 + l) * 8];
        half8 bh = *(const half8*)&W1h[(((gn << 3) + c) * 64 + l) * 8];
        half8 bl = *(const half8*)&W1l[(((gn << 3) + c) * 64 + l) * 8];
        acc  = __builtin_amdgcn_mfma_f32_16x16x32_f16(ah, bh, acc,  0, 0, 0);
        accl = __builtin_amdgcn_mfma_f32_16x16x32_f16(ah, bl, accl, 0, 0, 0);
        accl = __builtin_amdgcn_mfma_f32_16x16x32_f16(al, bh, accl, 0, 0, 0);
    }
    {
        int colb = (nf << 4) + (l & 15);
        float bb = b1[col0 + colb];
        #pragma unroll
        for (int j = 0; j < 4; j++) {
            float v = acc[j] + accl[j] * LOSC_INV + bb;
            zs[(mf << 4) + ((l >> 4) << 2) + j][colb] = tanhf(v);
        }
    }
    __syncthreads();
    // per-block row stats over the 64 local cols -> unique slot (no atomics)
    {
        int r = tid >> 4, c0 = (tid & 15) << 2;
        float s = 0.f, ss = 0.f;
        #pragma unroll
        for (int j = 0; j < 4; j++) { float v = zs[r][c0 + j]; s += v; ss += v * v; }
        #pragma unroll
        for (int o = 8; o; o >>= 1) { s += __shfl_xor(s, o); ss += __shfl_xor(ss, o); }
        if ((tid & 15) == 0) {
            float* st = stats1 + (((sIdx << 3) + blockIdx.y) * 512 + row0 + r) * 2;
            st[0] = s; st[1] = ss;
        }
    }
    // pack tanh output into single-f16 A-fragments for gemm2
    if (tid < 256) {
        int p = tid >> 6;              // (gm' 2) x (c' 2)
        int gmp = p & 1, cp = p >> 1;
        half8 hv;
        #pragma unroll
        for (int j = 0; j < 8; j++)
            hv[j] = (half_t)zs[(gmp << 4) + (l & 15)][(cp << 5) + ((l >> 4) << 3) + j];
        *(half8*)&t1[((((row0 >> 4) + gmp) * 16 + (col0 >> 5) + cp) * 64 + l) * 8] = hv;
    }
}

// GEMM2: t2 = tanh(rv*(t1 @ W2g^T) - m*rv*cg2 + cb2) -> single-f16 fragments + stats.
// LN folded: W2g = g1*W2 (hi/lo), cg2/cb2 precomputed. Raw t1 frags read from L2.
// Grid (16,8), 512 threads; block = 32 rows x 64 cols.
__global__ __launch_bounds__(512) void gemm2_kernel(
    const half_t* __restrict__ t1, const float* __restrict__ stats1,
    const half_t* __restrict__ W2gh, const half_t* __restrict__ W2gl,
    const float* __restrict__ cg2, const float* __restrict__ cb2,
    half_t* __restrict__ t2, float* __restrict__ stats2, int sIdx)
{
    __shared__ float zs[32][65];
    __shared__ float mr[32], rrs[32];
    const int tid = threadIdx.x, w = tid >> 6, l = tid & 63;
    const int row0 = blockIdx.x * 32, col0 = blockIdx.y * 64;

    // prologue: finalize LN1 stats for our 32 rows
    if (tid < 32) {
        float s = 0.f, ss = 0.f;
        #pragma unroll
        for (int p = 0; p < 8; p++) {
            const float* st = stats1 + (((sIdx << 3) + p) * 512 + row0 + tid) * 2;
            s += st[0]; ss += st[1];
        }
        float m = s * (1.f / 512.f);
        mr[tid] = m;
        rrs[tid] = rsqrtf(ss * (1.f / 512.f) - m * m + 1e-5f);
    }
    __syncthreads();

    const int mf = w & 1, nf = w >> 1;
    const int gn = (col0 >> 4) + nf;
    const int gmA = (row0 >> 4) + mf;
    f32x4 acc = {0.f, 0.f, 0.f, 0.f}, accl = {0.f, 0.f, 0.f, 0.f};
    for (int c = 0; c < 16; c++) {
        half8 ah = *(const half8*)&t1[((gmA * 16 + c) * 64 + l) * 8];
        half8 bh = *(const half8*)&W2gh[(((gn << 4) + c) * 64 + l) * 8];
        half8 bl = *(const half8*)&W2gl[(((gn << 4) + c) * 64 + l) * 8];
        acc  = __builtin_amdgcn_mfma_f32_16x16x32_f16(ah, bh, acc,  0, 0, 0);
        accl = __builtin_amdgcn_mfma_f32_16x16x32_f16(ah, bl, accl, 0, 0, 0);
    }
    {
        int colb = (nf << 4) + (l & 15);
        int col = col0 + colb;
        float cgv = cg2[col], cbv = cb2[col];
        #pragma unroll
        for (int j = 0; j < 4; j++) {
            int r = (mf << 4) + ((l >> 4) << 2) + j;
            float S = acc[j] + accl[j] * LOSC_INV;
            float v = rrs[r] * S - mr[r] * rrs[r] * cgv + cbv;
            zs[r][colb] = tanhf(v);
        }
    }
    __syncthreads();
    // stats epilogue (LN2 partials)
    {
        int r = tid >> 4, c0 = (tid & 15) << 2;
        float s = 0.f, ss = 0.f;
        #pragma unroll
        for (int j = 0; j < 4; j++) { float v = zs[r][c0 + j]; s += v; ss += v * v; }
        #pragma unroll
        for (int o = 8; o; o >>= 1) { s += __shfl_xor(s, o); ss += __shfl_xor(ss, o); }
        if ((tid & 15) == 0) {
            float* st = stats2 + (((sIdx << 3) + blockIdx.y) * 512 + row0 + r) * 2;
            st[0] = s; st[1] = ss;
        }
    }
    // pack t2 single-f16 frags
    if (tid < 256) {
        int p = tid >> 6;
        int gmp = p & 1, cp = p >> 1;
        half8 hv;
        #pragma unroll
        for (int j = 0; j < 8; j++)
            hv[j] = (half_t)zs[(gmp << 4) + (l & 15)][(cp << 5) + ((l >> 4) << 3) + j];
        *(half8*)&t2[((((row0 >> 4) + gmp) * 16 + (col0 >> 5) + cp) * 64 + l) * 8] = hv;
    }
}

// Stage 3: vf = rv2*(t2 @ W3g^T) - m2*rv2*cg3 + cb3;  h += dt*(vf . dX).
// 512 blocks = 16 row-groups (32 rows) x 32 col-groups (128 cols).
// Wave w owns n-group gn = cgi*8 + w (== hh); 2 m-frags; A read direct from L2.
__global__ __launch_bounds__(512) void stage3_kernel(
    const half_t* __restrict__ t2, const float* __restrict__ stats2,
    const half_t* __restrict__ W3gh, const float* __restrict__ cg3,
    const float* __restrict__ cb3, const float* __restrict__ coeffs,
    float* __restrict__ hbuf, int ii, float frac, int sIdx)
{
    __shared__ float dxs[32][17];        // 2.1 KB
    __shared__ float mvals[32], rvals[32];
    const int tid = threadIdx.x, w = tid >> 6, l = tid & 63;
    const int rg = blockIdx.x >> 5;      // 0..15 (32 rows)
    const int cgi = blockIdx.x & 31;     // 0..31 (128 cols)
    const int row0 = rg << 5;
    const int gn = (cgi << 3) + w;

    // spline derivative for the block's 32 rows (one element per thread)
    {
        int r = tid >> 4, d = tid & 15;
        int base = ((row0 + r) * (L_ - 1) + ii) * 64 + d;
        float c1 = coeffs[base + 16], c2 = coeffs[base + 32], c3 = coeffs[base + 48];
        dxs[r][d] = c1 + 2.0f * frac * c2 + 3.0f * (frac * frac) * c3;
    }
    // finalize LN2 stats for 32 rows
    if (tid < 32) {
        float s = 0.f, ss = 0.f;
        #pragma unroll
        for (int p = 0; p < 8; p++) {
            const float* st = stats2 + (((sIdx << 3) + p) * 512 + row0 + tid) * 2;
            s += st[0]; ss += st[1];
        }
        float m = s * (1.f / 512.f);
        mvals[tid] = m;
        rvals[tid] = rsqrtf(ss * (1.f / 512.f) - m * m + 1e-5f);
    }
    __syncthreads();

    const int gm0 = rg << 1;
    f32x4 acc0 = {0.f, 0.f, 0.f, 0.f}, acc1 = {0.f, 0.f, 0.f, 0.f};
    for (int c = 0; c < 16; c++) {
        half8 bh = *(const half8*)&W3gh[(((gn << 4) + c) * 64 + l) * 8];
        half8 a0 = *(const half8*)&t2[(((gm0 + 0) * 16 + c) * 64 + l) * 8];
        half8 a1 = *(const half8*)&t2[(((gm0 + 1) * 16 + c) * 64 + l) * 8];
        acc0 = __builtin_amdgcn_mfma_f32_16x16x32_f16(a0, bh, acc0, 0, 0, 0);
        acc1 = __builtin_amdgcn_mfma_f32_16x16x32_f16(a1, bh, acc1, 0, 0, 0);
    }

    // epilogue: affine LN fix + dX contraction + 16-lane reduce + unique-writer h RMW
    const int d = l & 15;
    const int o = (gn << 4) + d;
    const float cgv = cg3[o], cbv = cb3[o];
    #pragma unroll
    for (int mf = 0; mf < 2; mf++) {
        f32x4 a = mf ? acc1 : acc0;
        #pragma unroll
        for (int j = 0; j < 4; j++) {
            int rl = (mf << 4) + ((l >> 4) << 2) + j;
            float vf = rvals[rl] * a[j] - mvals[rl] * rvals[rl] * cgv + cbv;
            float s = vf * dxs[rl][d];
            s += __shfl_xor(s, 1);
            s += __shfl_xor(s, 2);
            s += __shfl_xor(s, 4);
            s += __shfl_xor(s, 8);
            if (d == 0) hbuf[(row0 + rl) * H_ + gn] += s * DT_;
        }
    }
}

// ---------------- launch ----------------

extern "C" void kernel_launch(void* const* d_in, const int* in_sizes, int n_in,
                              void* d_out, int out_size, void* d_ws, size_t ws_size,
                              hipStream_t stream) {
    const float* coeffs = (const float*)d_in[0];
    const float* W0  = (const float*)d_in[1];
    const float* b0  = (const float*)d_in[2];
    const float* W1  = (const float*)d_in[3];
    const float* b1  = (const float*)d_in[4];
    const float* g1  = (const float*)d_in[5];
    const float* be1 = (const float*)d_in[6];
    const float* W2  = (const float*)d_in[7];
    const float* b2  = (const float*)d_in[8];
    const float* g2  = (const float*)d_in[9];
    const float* be2 = (const float*)d_in[10];
    const float* W3  = (const float*)d_in[11];
    const float* b3  = (const float*)d_in[12];

    char* w = (char*)d_ws;
    float*  hbuf   = (float*)(w);                      // 512 KB
    half_t* t1     = (half_t*)(w + 524288);            // 512 KB
    half_t* t2     = (half_t*)(w + 1048576);           // 512 KB
    half_t* W1h    = (half_t*)(w + 1572864);           // 256 KB
    half_t* W1l    = (half_t*)(w + 1835008);           // 256 KB
    half_t* W2gh   = (half_t*)(w + 2097152);           // 512 KB
    half_t* W2gl   = (half_t*)(w + 2621440);           // 512 KB
    half_t* W3gh   = (half_t*)(w + 3145728);           // 4 MB
    float*  cg2    = (float*)(w + 7340032);            // 2 KB
    float*  cb2    = (float*)(w + 7342080);            // 2 KB
    float*  cg3    = (float*)(w + 7344128);            // 16 KB
    float*  cb3    = (float*)(w + 7360512);            // 16 KB
    float*  stats1 = (float*)(w + 7376896);            // 2 MB
    float*  stats2 = (float*)(w + 9474048);            // 2 MB   (ends ~11.6 MB)

    pack_frag_kernel<<<512, 256, 0, stream>>>(W1, W1h, W1l, 8, H_, V_ * H_);
    pack_frag_scaled2_kernel<<<1024, 256, 0, stream>>>(W2, g1, W2gh, W2gl, 16, V_, V_ * V_);
    pack_frag_scaled1_kernel<<<8192, 256, 0, stream>>>(W3, g2, W3gh, 16, V_, (H_ * D_) * V_);
    colvec_kernel<<<V_ / 4, 256, 0, stream>>>(W2, g1, be1, b2, cg2, cb2, V_, V_);
    colvec_kernel<<<(H_ * D_) / 4, 256, 0, stream>>>(W3, g2, be2, b3, cg3, cb3, H_ * D_, V_);
    h0_kernel<<<B_, H_, 0, stream>>>(coeffs, W0, b0, hbuf);

    for (int s = 0; s < STEPS_; s++) {
        float t = (float)s * 0.984375f;      // exact in fp32
        int ii = (int)t;
        if (ii > L_ - 2) ii = L_ - 2;
        float frac = t - (float)ii;
        gemm1_kernel<<<dim3(16, 8), 512, 0, stream>>>(hbuf, W1h, W1l, b1, t1, stats1, s);
        gemm2_kernel<<<dim3(16, 8), 512, 0, stream>>>(t1, stats1, W2gh, W2gl,
                                                      cg2, cb2, t2, stats2, s);
        stage3_kernel<<<512, 512, 0, stream>>>(t2, stats2, W3gh, cg3, cb3, coeffs,
                                               hbuf, ii, frac, s);
    }

    hipMemcpyAsync(d_out, hbuf, (size_t)B_ * H_ * sizeof(float),
                   hipMemcpyDeviceToDevice, stream);
}